// Round 2
// baseline (591.013 us; speedup 1.0000x reference)
//
#include <hip/hip_runtime.h>
#include <cstdint>
#include <cstddef>

#define D_DIM 20000
#define C4    5000           // D_DIM / 4 float4 chunks per row
#define K_SEL 1000
#define BLK   512
#define JPT   10             // float4 chunks per thread: BLK*JPT = 5120 >= C4

// monotonic float -> uint key (larger float => larger key)
__device__ __forceinline__ uint32_t f2k(float f) {
    uint32_t b = __float_as_uint(f);
    return (b & 0x80000000u) ? ~b : (b | 0x80000000u);
}
__device__ __forceinline__ float k2f(uint32_t k) {
    uint32_t b = (k & 0x80000000u) ? (k & 0x7FFFFFFFu) : ~k;
    return __uint_as_float(b);
}

__global__ void __launch_bounds__(BLK)
wta_kernel(const float* __restrict__ in, float* __restrict__ out) {
    const int row  = blockIdx.x;
    const int tid  = threadIdx.x;
    const int lane = tid & 63;
    const int wid  = tid >> 6;

    __shared__ uint32_t hist[256];
    __shared__ uint32_t suf[256];
    __shared__ uint32_t bc[3];     // 0: prefix/T, 1: kprime/budget, 2: bin count (m)
    __shared__ uint32_t waveTot[8];

    const float4* in4  = (const float4*)(in  + (size_t)row * D_DIM);
    float4*       out4 = (float4*)      (out + (size_t)row * D_DIM);

    // ---- load row into registers as keys (coalesced float4) ----
    uint32_t keys[JPT * 4];
    #pragma unroll
    for (int j = 0; j < JPT; ++j) {
        int c = j * BLK + tid;
        if (c < C4) {
            float4 v = in4[c];
            keys[4*j+0] = f2k(v.x);
            keys[4*j+1] = f2k(v.y);
            keys[4*j+2] = f2k(v.z);
            keys[4*j+3] = f2k(v.w);
        } else {
            keys[4*j+0] = 0u; keys[4*j+1] = 0u;
            keys[4*j+2] = 0u; keys[4*j+3] = 0u;   // key 0 = -NaN, below all real data
        }
    }

    if (tid == 0) { bc[0] = 0u; bc[1] = K_SEL; bc[2] = 0u; }

    // ---- 4-pass MSB-first radix select of the K-th largest key ----
    for (int p = 0; p < 4; ++p) {
        const int shift = 24 - 8 * p;
        if (tid < 256) hist[tid] = 0u;
        __syncthreads();                       // hist zeroed + bc visible

        const uint32_t prefix = bc[0];
        const uint32_t kp     = bc[1];
        const uint32_t maskHi = (p == 0) ? 0u : (0xFFFFFFFFu << (shift + 8));

        #pragma unroll
        for (int e = 0; e < JPT * 4; ++e) {
            uint32_t key = keys[e];
            if ((key & maskHi) == prefix)
                atomicAdd(&hist[(key >> shift) & 0xFFu], 1u);
        }
        __syncthreads();                       // histogram complete

        // wave 0: inclusive suffix-sum over 256 bins (4 bins/lane + shfl scan)
        if (tid < 64) {
            uint32_t h0 = hist[lane*4+0], h1 = hist[lane*4+1];
            uint32_t h2 = hist[lane*4+2], h3 = hist[lane*4+3];
            uint32_t t3 = h3, t2 = h2 + t3, t1 = h1 + t2, t0 = h0 + t1;
            uint32_t tot = t0;
            uint32_t inc = tot;
            #pragma unroll
            for (int d = 1; d < 64; d <<= 1) {
                uint32_t v = __shfl_down(inc, d, 64);
                if (lane + d < 64) inc += v;
            }
            uint32_t addR = inc - tot;         // sum of lane-totals to the right
            suf[lane*4+0] = t0 + addR;
            suf[lane*4+1] = t1 + addR;
            suf[lane*4+2] = t2 + addR;
            suf[lane*4+3] = t3 + addR;
        }
        __syncthreads();                       // suffix ready

        if (tid < 256) {
            uint32_t s     = suf[tid];
            uint32_t snext = (tid < 255) ? suf[tid + 1] : 0u;
            if (s >= kp && snext < kp) {       // exactly one thread matches
                bc[0] = prefix | ((uint32_t)tid << shift);
                bc[1] = kp - snext;            // rank within this bin
                bc[2] = s - snext;             // count of keys in this bin
            }
        }
        __syncthreads();                       // bc updated; suf free for reuse
    }

    const uint32_t T      = bc[0];             // exact K-th largest key
    const uint32_t budget = bc[1];             // how many keys == T to keep
    const uint32_t m      = bc[2];             // how many keys == T exist

    if (m == budget) {
        // ---- fast path: keep everything >= T (bit-exact pass-through) ----
        #pragma unroll
        for (int j = 0; j < JPT; ++j) {
            int c = j * BLK + tid;
            if (c < C4) {
                uint32_t k0 = keys[4*j+0], k1 = keys[4*j+1];
                uint32_t k2 = keys[4*j+2], k3 = keys[4*j+3];
                float4 o;
                o.x = (k0 >= T) ? k2f(k0) : 0.0f;
                o.y = (k1 >= T) ? k2f(k1) : 0.0f;
                o.z = (k2 >= T) ? k2f(k2) : 0.0f;
                o.w = (k3 >= T) ? k2f(k3) : 0.0f;
                out4[c] = o;
            }
        }
    } else {
        // ---- rare tie path: among keys == T keep only the `budget` smallest
        // global indices (matches jax.lax.top_k stable tie-break).
        // Global index of chunk c element e is 4*c+e; chunk order == (j, tid)
        // order, so an ordered block scan over j gives exact ranks.
        uint32_t running = 0;
        #pragma unroll
        for (int j = 0; j < JPT; ++j) {
            int c = j * BLK + tid;
            bool valid = (c < C4);
            uint32_t k0 = keys[4*j+0], k1 = keys[4*j+1];
            uint32_t k2 = keys[4*j+2], k3 = keys[4*j+3];
            uint32_t f0 = (valid && k0 == T) ? 1u : 0u;
            uint32_t f1 = (valid && k1 == T) ? 1u : 0u;
            uint32_t f2 = (valid && k2 == T) ? 1u : 0u;
            uint32_t f3 = (valid && k3 == T) ? 1u : 0u;
            uint32_t cnt = f0 + f1 + f2 + f3;

            // wave inclusive prefix sum of cnt
            uint32_t inc = cnt;
            #pragma unroll
            for (int d = 1; d < 64; d <<= 1) {
                uint32_t v = __shfl_up(inc, d, 64);
                if (lane >= d) inc += v;
            }
            if (lane == 63) waveTot[wid] = inc;
            __syncthreads();
            uint32_t waveBefore = 0, blockTot = 0;
            #pragma unroll
            for (int w = 0; w < 8; ++w) {
                uint32_t t = waveTot[w];
                blockTot += t;
                if (w < wid) waveBefore += t;
            }
            uint32_t base = running + waveBefore + (inc - cnt);
            uint32_t r0 = base;
            uint32_t r1 = base + f0;
            uint32_t r2 = base + f0 + f1;
            uint32_t r3 = base + f0 + f1 + f2;
            if (valid) {
                float4 o;
                o.x = (k0 > T || (f0 && r0 < budget)) ? k2f(k0) : 0.0f;
                o.y = (k1 > T || (f1 && r1 < budget)) ? k2f(k1) : 0.0f;
                o.z = (k2 > T || (f2 && r2 < budget)) ? k2f(k2) : 0.0f;
                o.w = (k3 > T || (f3 && r3 < budget)) ? k2f(k3) : 0.0f;
                out4[c] = o;
            }
            running += blockTot;
            __syncthreads();                   // waveTot reuse next j
        }
    }
}

extern "C" void kernel_launch(void* const* d_in, const int* in_sizes, int n_in,
                              void* d_out, int out_size, void* d_ws, size_t ws_size,
                              hipStream_t stream) {
    const float* in  = (const float*)d_in[0];
    float*       out = (float*)d_out;
    const int B = in_sizes[0] / D_DIM;         // 4096 rows
    wta_kernel<<<dim3(B), dim3(BLK), 0, stream>>>(in, out);
}

// Round 4
// 558.491 us; speedup vs baseline: 1.0582x; 1.0582x over previous
//
#include <hip/hip_runtime.h>
#include <cstdint>
#include <cstddef>

#define D_DIM 20000
#define C4    5000           // D_DIM / 4 float4 chunks per row
#define K_SEL 1000
#define BLK   256
#define JPT   20             // float4 chunks per thread: BLK*JPT = 5120 >= C4
#define NW    (BLK / 64)     // 4 waves per block
#define NCOPY 16             // histogram privatization copies (indexed lane%16)
#define CAP   1024           // candidate buffer for exact tail select

typedef float  vf4 __attribute__((ext_vector_type(4)));   // native vector: OK for nontemporal builtin
typedef unsigned int vu4 __attribute__((ext_vector_type(4)));

// monotonic float -> uint key (larger float => larger key)
__device__ __forceinline__ uint32_t f2k(float f) {
    uint32_t b = __float_as_uint(f);
    return (b & 0x80000000u) ? ~b : (b | 0x80000000u);
}
__device__ __forceinline__ float k2f(uint32_t k) {
    uint32_t b = (k & 0x80000000u) ? (k & 0x7FFFFFFFu) : ~k;
    return __uint_as_float(b);
}

// One 8-bit MSB-first radix-select pass over register-resident keys.
// hist layout: hist[bin*NCOPY + copy] — copies contiguous so the reduction
// reads uint4; hot-bin atomics spread over 16 banks / 16 addresses.
__device__ __forceinline__ void radix_pass(
        const uint32_t* keys, int shift, uint32_t maskHi,
        uint32_t* hist, volatile uint32_t* bc, uint32_t* ccnt,
        int tid, int lane, bool zero_ccnt) {
    // zero histogram (4096 words, 256 threads x 4 uint4)
    uint4 z; z.x = 0u; z.y = 0u; z.z = 0u; z.w = 0u;
    #pragma unroll
    for (int i = 0; i < 4; ++i) ((uint4*)hist)[tid * 4 + i] = z;
    if (zero_ccnt && tid == 0) *ccnt = 0u;
    __syncthreads();                       // hist zeroed + bc visible

    const uint32_t prefix = bc[0];
    const uint32_t kp     = bc[1];
    const int      copy   = tid & (NCOPY - 1);

    #pragma unroll
    for (int e = 0; e < JPT * 4; ++e) {
        uint32_t key = keys[e];
        if ((key & maskHi) == prefix)
            atomicAdd(&hist[(((key >> shift) & 0xFFu) * NCOPY) + copy], 1u);
    }
    __syncthreads();                       // histogram complete

    // wave 0: reduce 16 copies, suffix-scan 256 bins, pick bin — no LDS round-trip
    if (tid < 64) {
        uint32_t h[4];
        #pragma unroll
        for (int b = 0; b < 4; ++b) {
            const uint4* p4 = (const uint4*)&hist[(4 * lane + b) * NCOPY];
            uint4 a = p4[0], q = p4[1], r = p4[2], s = p4[3];
            h[b] = a.x + a.y + a.z + a.w + q.x + q.y + q.z + q.w
                 + r.x + r.y + r.z + r.w + s.x + s.y + s.z + s.w;
        }
        uint32_t t3 = h[3], t2 = h[2] + t3, t1 = h[1] + t2, t0 = h[0] + t1;
        uint32_t tot = t0;
        uint32_t inc = tot;
        #pragma unroll
        for (int d = 1; d < 64; d <<= 1) {
            uint32_t v = __shfl_down(inc, d, 64);
            if (lane + d < 64) inc += v;
        }
        uint32_t addR = inc - tot;         // sum over lanes to the right
        uint32_t s0 = t0 + addR, s1 = t1 + addR, s2 = t2 + addR, s3 = t3 + addR;
        uint32_t sv[4]  = { s0, s1, s2, s3 };
        uint32_t snv[4] = { s1, s2, s3, addR };   // suffix of bin+1
        #pragma unroll
        for (int i = 0; i < 4; ++i) {
            if (sv[i] >= kp && snv[i] < kp) {     // exactly one lane/bin matches
                bc[0] = prefix | ((uint32_t)(4 * lane + i) << shift);
                bc[1] = kp - snv[i];              // rank within this bin
                bc[2] = sv[i] - snv[i];           // count of keys in this bin
            }
        }
    }
    __syncthreads();                       // bc updated
}

__global__ void __launch_bounds__(BLK)
wta_kernel(const float* __restrict__ in, float* __restrict__ out) {
    const int row  = blockIdx.x;
    const int tid  = threadIdx.x;
    const int lane = tid & 63;
    const int wid  = tid >> 6;

    __shared__ uint32_t hist[256 * NCOPY];   // 16 KB
    __shared__ uint32_t cand[CAP];           // 4 KB
    __shared__ uint32_t ccnt;
    __shared__ uint32_t bc[3];     // 0: prefix/T, 1: kprime/budget, 2: bin count (m)
    __shared__ uint32_t waveTot[NW];

    const float4* in4  = (const float4*)(in  + (size_t)row * D_DIM);
    vf4*          out4 = (vf4*)         (out + (size_t)row * D_DIM);

    // ---- load row into registers as keys (coalesced float4) ----
    uint32_t keys[JPT * 4];
    #pragma unroll
    for (int j = 0; j < JPT; ++j) {
        int c = j * BLK + tid;
        if (c < C4) {
            float4 v = in4[c];
            keys[4*j+0] = f2k(v.x);
            keys[4*j+1] = f2k(v.y);
            keys[4*j+2] = f2k(v.z);
            keys[4*j+3] = f2k(v.w);
        } else {
            keys[4*j+0] = 0u; keys[4*j+1] = 0u;
            keys[4*j+2] = 0u; keys[4*j+3] = 0u;   // key 0 = -NaN, below all real data
        }
    }

    if (tid == 0) { bc[0] = 0u; bc[1] = K_SEL; bc[2] = 0u; }
    // (visibility ensured by the sync inside radix_pass after hist zeroing)

    // ---- resolve top 16 bits via two radix passes ----
    radix_pass(keys, 24, 0x00000000u, hist, bc, &ccnt, tid, lane, false);
    radix_pass(keys, 16, 0xFF000000u, hist, bc, &ccnt, tid, lane, true);

    const uint32_t prefix16 = bc[0];
    const uint32_t kp16     = bc[1];
    const uint32_t m16      = bc[2];

    if (m16 <= CAP) {
        // ---- compact the surviving bin (expected ~10 elems) and exact-select ----
        #pragma unroll
        for (int e = 0; e < JPT * 4; ++e) {
            uint32_t key = keys[e];
            if ((key & 0xFFFF0000u) == prefix16) {
                uint32_t idx = atomicAdd(&ccnt, 1u);
                if (idx < CAP) cand[idx] = key;
            }
        }
        __syncthreads();
        if (wid == 0) {
            uint32_t c = ccnt;                    // == m16
            for (uint32_t idx = lane; idx < c; idx += 64) {
                uint32_t x = cand[idx];
                uint32_t gt = 0, eq = 0;
                for (uint32_t j = 0; j < c; ++j) {
                    uint32_t y = cand[j];          // broadcast read
                    gt += (y > x) ? 1u : 0u;
                    eq += (y == x) ? 1u : 0u;
                }
                if (gt < kp16 && kp16 <= gt + eq) { // unique value window
                    bc[0] = x;                      // T
                    bc[1] = kp16 - gt;              // budget among ==T
                    bc[2] = eq;                     // m
                }
            }
        }
        __syncthreads();
    } else {
        // ---- fallback (pathological ties): finish radix to 32 bits ----
        radix_pass(keys, 8, 0xFFFF0000u, hist, bc, &ccnt, tid, lane, false);
        radix_pass(keys, 0, 0xFFFFFF00u, hist, bc, &ccnt, tid, lane, false);
    }

    const uint32_t T      = bc[0];             // exact K-th largest key
    const uint32_t budget = bc[1];             // how many keys == T to keep
    const uint32_t m      = bc[2];             // how many keys == T exist

    if (m == budget) {
        // ---- fast path: keep everything >= T (bit-exact pass-through) ----
        #pragma unroll
        for (int j = 0; j < JPT; ++j) {
            int c = j * BLK + tid;
            if (c < C4) {
                uint32_t k0 = keys[4*j+0], k1 = keys[4*j+1];
                uint32_t k2 = keys[4*j+2], k3 = keys[4*j+3];
                vf4 o;
                o.x = (k0 >= T) ? k2f(k0) : 0.0f;
                o.y = (k1 >= T) ? k2f(k1) : 0.0f;
                o.z = (k2 >= T) ? k2f(k2) : 0.0f;
                o.w = (k3 >= T) ? k2f(k3) : 0.0f;
                __builtin_nontemporal_store(o, &out4[c]);
            }
        }
    } else {
        // ---- rare tie path: among keys == T keep only the `budget` smallest
        // global indices (matches jax.lax.top_k stable tie-break). Chunk order
        // == (j, tid) order, so an ordered block scan gives exact ranks.
        uint32_t running = 0;
        #pragma unroll
        for (int j = 0; j < JPT; ++j) {
            int c = j * BLK + tid;
            bool valid = (c < C4);
            uint32_t k0 = keys[4*j+0], k1 = keys[4*j+1];
            uint32_t k2 = keys[4*j+2], k3 = keys[4*j+3];
            uint32_t f0 = (valid && k0 == T) ? 1u : 0u;
            uint32_t f1 = (valid && k1 == T) ? 1u : 0u;
            uint32_t f2 = (valid && k2 == T) ? 1u : 0u;
            uint32_t f3 = (valid && k3 == T) ? 1u : 0u;
            uint32_t cnt = f0 + f1 + f2 + f3;

            uint32_t inc = cnt;
            #pragma unroll
            for (int d = 1; d < 64; d <<= 1) {
                uint32_t v = __shfl_up(inc, d, 64);
                if (lane >= d) inc += v;
            }
            if (lane == 63) waveTot[wid] = inc;
            __syncthreads();
            uint32_t waveBefore = 0, blockTot = 0;
            #pragma unroll
            for (int w = 0; w < NW; ++w) {
                uint32_t t = waveTot[w];
                blockTot += t;
                if (w < wid) waveBefore += t;
            }
            uint32_t base = running + waveBefore + (inc - cnt);
            uint32_t r0 = base;
            uint32_t r1 = base + f0;
            uint32_t r2 = base + f0 + f1;
            uint32_t r3 = base + f0 + f1 + f2;
            if (valid) {
                float4 o;
                o.x = (k0 > T || (f0 && r0 < budget)) ? k2f(k0) : 0.0f;
                o.y = (k1 > T || (f1 && r1 < budget)) ? k2f(k1) : 0.0f;
                o.z = (k2 > T || (f2 && r2 < budget)) ? k2f(k2) : 0.0f;
                o.w = (k3 > T || (f3 && r3 < budget)) ? k2f(k3) : 0.0f;
                ((float4*)out4)[c] = o;
            }
            running += blockTot;
            __syncthreads();                   // waveTot reuse next j
        }
    }
}

extern "C" void kernel_launch(void* const* d_in, const int* in_sizes, int n_in,
                              void* d_out, int out_size, void* d_ws, size_t ws_size,
                              hipStream_t stream) {
    const float* in  = (const float*)d_in[0];
    float*       out = (float*)d_out;
    const int B = in_sizes[0] / D_DIM;         // 4096 rows
    wta_kernel<<<dim3(B), dim3(BLK), 0, stream>>>(in, out);
}